// Round 1
// baseline (188.650 us; speedup 1.0000x reference)
//
#include <hip/hip_runtime.h>

// Sampler reduces to row-wise argmax (temperature>0 is monotone; top-p/top-k
// never mask the rank-0 token; softmax is monotone). out[row] = argmax(row),
// first-index tie-break (jnp.argmax semantics).
//
// 131 MB fp32 read, 1 KB write -> pure memory-bound. Previous shape
// (256 blocks x 1024 thr = 1 block/CU, 16 waves/CU) left ~30% of achievable
// HBM BW on the table vs the 86%-of-peak fill kernels. This version: 2-phase.
//   Phase 1: 2048 blocks (256 rows x 8 slices) x 256 thr -> 8 blocks/CU,
//            32 waves/CU (full occupancy), 4 independent float4 streams.
//            Writes one (val,idx) partial per block to workspace (8 B,
//            deterministically overwritten every run -> re-poison safe).
//   Phase 2: 256 blocks x 64 thr, shuffle-reduce 8 partials/row.

#define VOCAB  128000
#define BATCH  256
#define NSLICE 8
#define SLICE_ELEMS (VOCAB / NSLICE)   // 16000 floats per slice
#define SLICE_F4    (SLICE_ELEMS / 4)  // 4000 float4 per slice
#define BLK1   256
#define NFULL1 (SLICE_F4 / (BLK1 * 4)) // 3 full x4 iterations (3072 f4)

#define NEG_INF (-3.402823466e+38f)

__device__ __forceinline__ void upd(float v, int idx, float& b, int& bi) {
    if (v > b) { b = v; bi = idx; }
}

__device__ __forceinline__ void upd4(const float4& v, int base, float& b, int& bi) {
    upd(v.x, base + 0, b, bi);
    upd(v.y, base + 1, b, bi);
    upd(v.z, base + 2, b, bi);
    upd(v.w, base + 3, b, bi);
}

// ---------------- Phase 1: per-(row,slice) partial argmax ----------------
__global__ __launch_bounds__(BLK1, 8) void argmax_partial(
    const float* __restrict__ logits, int2* __restrict__ part) {
    const int row   = blockIdx.x >> 3;   // 0..255
    const int slice = blockIdx.x & 7;    // 0..7
    const float4* __restrict__ p = reinterpret_cast<const float4*>(
        logits + (size_t)row * VOCAB + slice * SLICE_ELEMS);
    const int cbase = slice * SLICE_ELEMS;  // absolute column of slice start

    float b0 = NEG_INF, b1 = NEG_INF, b2 = NEG_INF, b3 = NEG_INF;
    int   i0 = 0x7fffffff, i1 = 0x7fffffff, i2 = 0x7fffffff, i3 = 0x7fffffff;

    int j = threadIdx.x;
    #pragma unroll 1
    for (int it = 0; it < NFULL1; ++it, j += 4 * BLK1) {
        // 4 independent loads in flight before any compare consumes them
        float4 v0 = p[j];
        float4 v1 = p[j + BLK1];
        float4 v2 = p[j + 2 * BLK1];
        float4 v3 = p[j + 3 * BLK1];
        upd4(v0, cbase + ((j) << 2),            b0, i0);
        upd4(v1, cbase + ((j + BLK1) << 2),     b1, i1);
        upd4(v2, cbase + ((j + 2 * BLK1) << 2), b2, i2);
        upd4(v3, cbase + ((j + 3 * BLK1) << 2), b3, i3);
    }
    // tail: f4 indices [3072, 4000)
    for (; j < SLICE_F4; j += BLK1) {
        float4 v = p[j];
        upd4(v, cbase + (j << 2), b0, i0);
    }

    // merge 4 streams; equal values -> lower index
    float best = b0; int bestIdx = i0;
    if (b1 > best || (b1 == best && i1 < bestIdx)) { best = b1; bestIdx = i1; }
    if (b2 > best || (b2 == best && i2 < bestIdx)) { best = b2; bestIdx = i2; }
    if (b3 > best || (b3 == best && i3 < bestIdx)) { best = b3; bestIdx = i3; }

    // wave-64 shuffle reduce, tie-break toward lower index
    #pragma unroll
    for (int off = 32; off > 0; off >>= 1) {
        float ov = __shfl_down(best, off, 64);
        int   oi = __shfl_down(bestIdx, off, 64);
        if (ov > best || (ov == best && oi < bestIdx)) { best = ov; bestIdx = oi; }
    }

    // cross-wave reduce via LDS (4 waves)
    __shared__ float s_val[4];
    __shared__ int   s_idx[4];
    const int lane = threadIdx.x & 63;
    const int wave = threadIdx.x >> 6;
    if (lane == 0) { s_val[wave] = best; s_idx[wave] = bestIdx; }
    __syncthreads();

    if (wave == 0) {
        float v  = (lane < 4) ? s_val[lane] : NEG_INF;
        int   ix = (lane < 4) ? s_idx[lane] : 0x7fffffff;
        #pragma unroll
        for (int off = 2; off > 0; off >>= 1) {
            float ov = __shfl_down(v, off, 64);
            int   oi = __shfl_down(ix, off, 64);
            if (ov > v || (ov == v && oi < ix)) { v = ov; ix = oi; }
        }
        if (lane == 0) part[blockIdx.x] = make_int2(__float_as_int(v), ix);
    }
}

// ---------------- Phase 2: reduce 8 partials per row ----------------
__global__ __launch_bounds__(64, 1) void argmax_final(
    const int2* __restrict__ part, int* __restrict__ out) {
    const int row  = blockIdx.x;
    const int lane = threadIdx.x;  // 0..63
    float v  = NEG_INF;
    int   ix = 0x7fffffff;
    if (lane < NSLICE) {
        int2 e = part[row * NSLICE + lane];
        v  = __int_as_float(e.x);
        ix = e.y;
    }
    #pragma unroll
    for (int off = 4; off > 0; off >>= 1) {
        float ov = __shfl_down(v, off, 64);
        int   oi = __shfl_down(ix, off, 64);
        if (ov > v || (ov == v && oi < ix)) { v = ov; ix = oi; }
    }
    if (lane == 0) out[row] = ix;
}

// ---------------- Fallback: proven single-kernel path ----------------
#define BLK   1024
#define NT4   (VOCAB / 4)
#define NFULL (NT4 / (BLK * 4))

__global__ __launch_bounds__(BLK, 1) void argmax_rows(
    const float* __restrict__ logits, int* __restrict__ out) {
    const int row = blockIdx.x;
    const int tid = threadIdx.x;
    const float4* __restrict__ rowp =
        reinterpret_cast<const float4*>(logits + (size_t)row * VOCAB);

    float b0 = NEG_INF, b1 = NEG_INF, b2 = NEG_INF, b3 = NEG_INF;
    int   i0 = 0x7fffffff, i1 = 0x7fffffff, i2 = 0x7fffffff, i3 = 0x7fffffff;

    int i = tid;
    #pragma unroll 1
    for (int it = 0; it < NFULL; ++it, i += 4 * BLK) {
        float4 v0 = rowp[i];
        float4 v1 = rowp[i + BLK];
        float4 v2 = rowp[i + 2 * BLK];
        float4 v3 = rowp[i + 3 * BLK];
        upd4(v0, (i) << 2,            b0, i0);
        upd4(v1, (i + BLK) << 2,      b1, i1);
        upd4(v2, (i + 2 * BLK) << 2,  b2, i2);
        upd4(v3, (i + 3 * BLK) << 2,  b3, i3);
    }
    for (; i < NT4; i += BLK) {
        float4 v = rowp[i];
        upd4(v, i << 2, b0, i0);
    }

    float best = b0; int bestIdx = i0;
    if (b1 > best || (b1 == best && i1 < bestIdx)) { best = b1; bestIdx = i1; }
    if (b2 > best || (b2 == best && i2 < bestIdx)) { best = b2; bestIdx = i2; }
    if (b3 > best || (b3 == best && i3 < bestIdx)) { best = b3; bestIdx = i3; }

    #pragma unroll
    for (int off = 32; off > 0; off >>= 1) {
        float ov = __shfl_down(best, off, 64);
        int   oi = __shfl_down(bestIdx, off, 64);
        if (ov > best || (ov == best && oi < bestIdx)) { best = ov; bestIdx = oi; }
    }

    __shared__ float s_val[16];
    __shared__ int   s_idx[16];
    const int lane = tid & 63;
    const int wave = tid >> 6;
    if (lane == 0) { s_val[wave] = best; s_idx[wave] = bestIdx; }
    __syncthreads();

    if (wave == 0) {
        float v  = (lane < 16) ? s_val[lane] : NEG_INF;
        int   ix = (lane < 16) ? s_idx[lane] : 0x7fffffff;
        #pragma unroll
        for (int off = 8; off > 0; off >>= 1) {
            float ov = __shfl_down(v, off, 64);
            int   oi = __shfl_down(ix, off, 64);
            if (ov > v || (ov == v && oi < ix)) { v = ov; ix = oi; }
        }
        if (lane == 0) out[row] = ix;
    }
}

extern "C" void kernel_launch(void* const* d_in, const int* in_sizes, int n_in,
                              void* d_out, int out_size, void* d_ws, size_t ws_size,
                              hipStream_t stream) {
    const float* logits = (const float*)d_in[0];
    int* out = (int*)d_out;
    const size_t need_ws = (size_t)BATCH * NSLICE * sizeof(int2);  // 16 KB
    if (ws_size >= need_ws && d_ws != nullptr) {
        int2* part = (int2*)d_ws;
        argmax_partial<<<BATCH * NSLICE, BLK1, 0, stream>>>(logits, part);
        argmax_final<<<BATCH, 64, 0, stream>>>(part, out);
    } else {
        argmax_rows<<<BATCH, BLK, 0, stream>>>(logits, out);
    }
}

// Round 5
// 172.675 us; speedup vs baseline: 1.0925x; 1.0925x over previous
//
#include <hip/hip_runtime.h>

// Sampler reduces to row-wise argmax (temperature>0 is monotone; top-p/top-k
// never mask the rank-0 token; softmax is monotone). out[row] = argmax(row),
// first-index tie-break (jnp.argmax semantics).
//
// 131 MB fp32 read, 1 KB write -> pure memory-bound. Round-1 evidence:
// 2-phase / 32-wave-CU version gained nothing on the scan and paid +4.6 us
// for the extra dispatch -> NOT occupancy-bound; single dispatch mandatory.
// This version: single kernel, 256 blocks x 1024 thr (1 block/CU), with
//   - 8 independent (best,idx) streams: 8 float4 loads in flight per wave
//     (128 KB/CU outstanding) to cover ~900cy poisoned-L3 HBM miss latency
//   - non-temporal loads: logits are stream-once (1 GB of poison fills evicts
//     L3 between iterations); nt skips cache allocation on the read path.
// NOTE: __builtin_nontemporal_load rejects HIP_vector_type<float,4>* -- use a
// clang ext_vector_type(4) float vector instead (r2 compile fix).
// (Rounds 3-4 were infra failures — this source is the unmodified resubmit.)

#define VOCAB 128000
#define NT4   (VOCAB / 4)     // 32000 float4 per row
#define BLK   1024
#define NF8   (NT4 / (BLK * 8))  // 3 full x8 iterations -> [0, 24576)

#define NEG_INF (-3.402823466e+38f)

typedef float f32x4 __attribute__((ext_vector_type(4)));

__device__ __forceinline__ void upd(float v, int idx, float& b, int& bi) {
    if (v > b) { b = v; bi = idx; }
}

__device__ __forceinline__ void upd4(const f32x4& v, int base, float& b, int& bi) {
    upd(v.x, base + 0, b, bi);
    upd(v.y, base + 1, b, bi);
    upd(v.z, base + 2, b, bi);
    upd(v.w, base + 3, b, bi);
}

__device__ __forceinline__ void mergeTo(float& best, int& bestIdx, float v, int ix) {
    // equal values -> lower absolute index (jnp.argmax first-index semantics)
    if (v > best || (v == best && ix < bestIdx)) { best = v; bestIdx = ix; }
}

__global__ __launch_bounds__(BLK, 1) void argmax_rows(
    const float* __restrict__ logits, int* __restrict__ out) {
    const int row = blockIdx.x;
    const int tid = threadIdx.x;
    const f32x4* __restrict__ rowp =
        reinterpret_cast<const f32x4*>(logits + (size_t)row * VOCAB);

    float b0 = NEG_INF, b1 = NEG_INF, b2 = NEG_INF, b3 = NEG_INF;
    float b4 = NEG_INF, b5 = NEG_INF, b6 = NEG_INF, b7 = NEG_INF;
    int   i0 = 0x7fffffff, i1 = 0x7fffffff, i2 = 0x7fffffff, i3 = 0x7fffffff;
    int   i4 = 0x7fffffff, i5 = 0x7fffffff, i6 = 0x7fffffff, i7 = 0x7fffffff;

    int i = tid;
    #pragma unroll 1
    for (int it = 0; it < NF8; ++it, i += 8 * BLK) {
        // 8 independent nt loads issued before any compare consumes them
        f32x4 v0 = __builtin_nontemporal_load(rowp + i);
        f32x4 v1 = __builtin_nontemporal_load(rowp + i + BLK);
        f32x4 v2 = __builtin_nontemporal_load(rowp + i + 2 * BLK);
        f32x4 v3 = __builtin_nontemporal_load(rowp + i + 3 * BLK);
        f32x4 v4 = __builtin_nontemporal_load(rowp + i + 4 * BLK);
        f32x4 v5 = __builtin_nontemporal_load(rowp + i + 5 * BLK);
        f32x4 v6 = __builtin_nontemporal_load(rowp + i + 6 * BLK);
        f32x4 v7 = __builtin_nontemporal_load(rowp + i + 7 * BLK);
        upd4(v0, (i) << 2,            b0, i0);
        upd4(v1, (i + BLK) << 2,      b1, i1);
        upd4(v2, (i + 2 * BLK) << 2,  b2, i2);
        upd4(v3, (i + 3 * BLK) << 2,  b3, i3);
        upd4(v4, (i + 4 * BLK) << 2,  b4, i4);
        upd4(v5, (i + 5 * BLK) << 2,  b5, i5);
        upd4(v6, (i + 6 * BLK) << 2,  b6, i6);
        upd4(v7, (i + 7 * BLK) << 2,  b7, i7);
    }
    // one x4 group: [24576, 28672)
    {
        f32x4 v0 = __builtin_nontemporal_load(rowp + i);
        f32x4 v1 = __builtin_nontemporal_load(rowp + i + BLK);
        f32x4 v2 = __builtin_nontemporal_load(rowp + i + 2 * BLK);
        f32x4 v3 = __builtin_nontemporal_load(rowp + i + 3 * BLK);
        upd4(v0, (i) << 2,            b0, i0);
        upd4(v1, (i + BLK) << 2,      b1, i1);
        upd4(v2, (i + 2 * BLK) << 2,  b2, i2);
        upd4(v3, (i + 3 * BLK) << 2,  b3, i3);
        i += 4 * BLK;
    }
    // tail: float4 indices [28672, 32000)
    for (; i < NT4; i += BLK) {
        f32x4 v = __builtin_nontemporal_load(rowp + i);
        upd4(v, i << 2, b0, i0);
    }

    // merge 8 streams; ties -> lower index
    float best = b0; int bestIdx = i0;
    mergeTo(best, bestIdx, b1, i1);
    mergeTo(best, bestIdx, b2, i2);
    mergeTo(best, bestIdx, b3, i3);
    mergeTo(best, bestIdx, b4, i4);
    mergeTo(best, bestIdx, b5, i5);
    mergeTo(best, bestIdx, b6, i6);
    mergeTo(best, bestIdx, b7, i7);

    // wave-64 shuffle reduce, tie-break toward lower index
    #pragma unroll
    for (int off = 32; off > 0; off >>= 1) {
        float ov = __shfl_down(best, off, 64);
        int   oi = __shfl_down(bestIdx, off, 64);
        mergeTo(best, bestIdx, ov, oi);
    }

    // cross-wave reduce via LDS (16 waves)
    __shared__ float s_val[16];
    __shared__ int   s_idx[16];
    const int lane = tid & 63;
    const int wave = tid >> 6;
    if (lane == 0) { s_val[wave] = best; s_idx[wave] = bestIdx; }
    __syncthreads();

    if (wave == 0) {
        float v  = (lane < 16) ? s_val[lane] : NEG_INF;
        int   ix = (lane < 16) ? s_idx[lane] : 0x7fffffff;
        #pragma unroll
        for (int off = 8; off > 0; off >>= 1) {
            float ov = __shfl_down(v, off, 64);
            int   oi = __shfl_down(ix, off, 64);
            mergeTo(v, ix, ov, oi);
        }
        if (lane == 0) out[row] = ix;
    }
}

extern "C" void kernel_launch(void* const* d_in, const int* in_sizes, int n_in,
                              void* d_out, int out_size, void* d_ws, size_t ws_size,
                              hipStream_t stream) {
    const float* logits = (const float*)d_in[0];
    int* out = (int*)d_out;
    argmax_rows<<<256, BLK, 0, stream>>>(logits, out);
}